// Round 4
// baseline (62.906 us; speedup 1.0000x reference)
//
#include <hip/hip_runtime.h>

typedef unsigned short u16;
typedef __bf16 bf16x8 __attribute__((ext_vector_type(8)));
typedef float f32x4 __attribute__((ext_vector_type(4)));

#define B_   16
#define H_   56
#define W_   56
#define C_   128
#define OH_  54
#define OW_  54
#define NF_  256
#define KF_  1152           // C_*9
#define M_   46656          // B_*OH_*OW_
#define NNZ_ 58982

#define XB_ELEMS (B_*H_*W_*C_)       // 6422528
#define WT_ELEMS (36*4*256*8)        // 294912 (pre-tiled [kt][ks][col][8])

__device__ __forceinline__ u16 f2bf(float f) {
    unsigned u = __float_as_uint(f);
    u += 0x7FFFu + ((u >> 16) & 1u);
    return (u16)(u >> 16);
}

__device__ __forceinline__ void gload16(const void* g, void* l) {
    __builtin_amdgcn_global_load_lds(
        (const __attribute__((address_space(1))) unsigned int*)g,
        (__attribute__((address_space(3))) unsigned int*)l,
        16, 0, 0);
}

// ---- kernel 1: x f32 -> bf16 (vectorized 8/thread) ----
__global__ __launch_bounds__(256) void cvt_x_kernel(const float* __restrict__ x,
                                                    u16* __restrict__ xb) {
    int i = (blockIdx.x * 256 + threadIdx.x) * 8;
    float4 v0 = *(const float4*)(x + i);
    float4 v1 = *(const float4*)(x + i + 4);
    union { u16 u[8]; uint4 v; } r;
    r.u[0] = f2bf(v0.x); r.u[1] = f2bf(v0.y); r.u[2] = f2bf(v0.z); r.u[3] = f2bf(v0.w);
    r.u[4] = f2bf(v1.x); r.u[5] = f2bf(v1.y); r.u[6] = f2bf(v1.z); r.u[7] = f2bf(v1.w);
    *(uint4*)(xb + i) = r.v;
}

// ---- kernel 2: scatter sparse values into PRE-TILED W: [kt][ks][col][8] ----
__global__ __launch_bounds__(256) void scatter_kernel(const float* __restrict__ kv,
                                                      const int* __restrict__ idx,
                                                      u16* __restrict__ wt) {
    int t = blockIdx.x * 256 + threadIdx.x;
    if (t >= NNZ_) return;
    int k   = idx[2*t];      // row in [0,1152)
    int col = idx[2*t + 1];  // col in [0,256)
    int kt = k >> 5, ks = (k >> 3) & 3, e = k & 7;
    wt[(kt * 4 + ks) * 2048 + col * 8 + e] = f2bf(kv[t]);
}

// ---- kernel 3: implicit-GEMM conv, 4-deep ring + counted vmcnt (T3+T4) ----
// BM=64 (729 blocks exact), BN=256, BK=32, 4 waves of 64x64.
// Ring of 4 LDS tile-buffers (80KB, 2 blocks/CU). Iter kt: wait vmcnt(10)
// (tiles kt+1,kt+2 stay in flight) -> s_barrier -> compute buf[kt&3] ->
// issue tile kt+3 into buf[(kt+3)&3]. Tail drains 10/10/5/0.
__global__ __launch_bounds__(256, 2) void spconv_gemm(const u16* __restrict__ xb,
                                                      const u16* __restrict__ wt,
                                                      const float* __restrict__ bias,
                                                      float* __restrict__ out) {
    __shared__ __align__(16) u16 As[4][64 * 32];      // 4 x 4 KB
    __shared__ __align__(16) u16 Bs[4][4 * 256 * 8];  // 4 x 16 KB

    const int t    = threadIdx.x;
    const int lane = t & 63;
    const int wid  = t >> 6;

    // bijective XCD swizzle (nwg=729 -> m204 formula)
    const int nwg = gridDim.x;
    const int q = nwg >> 3, r = nwg & 7;
    const int xcd = blockIdx.x & 7, inner = blockIdx.x >> 3;
    const int wg = (xcd < r ? xcd * (q + 1) : r * (q + 1) + (xcd - r) * q) + inner;
    const int m0 = wg * 64;

    // A staging: thread t stages cell (arow, kc); 4 lanes/row -> 64B sectors.
    // kc-XOR swizzle applied on the global SOURCE (dest stays lane-linear).
    const int arow = (wid << 4) | (lane >> 2);          // 0..63
    const int kc   = lane & 3;
    const int kcs  = kc ^ (arow & 3) ^ ((arow >> 2) & 3);
    const int kco  = kcs * 8;
    int mg  = m0 + arow;
    int bb  = mg / (OH_ * OW_);
    int rem = mg % (OH_ * OW_);
    int ii  = rem / OW_;
    int jj  = rem % OW_;
    const u16* a_base = xb + ((bb * H_ + ii) * W_ + jj) * C_;
    const int a_dst = t * 8;
    const int b_dst = t * 8;

    f32x4 acc[4][4];
    const f32x4 zz = {0.f, 0.f, 0.f, 0.f};
#pragma unroll
    for (int i = 0; i < 4; ++i)
#pragma unroll
        for (int j = 0; j < 4; ++j) acc[i][j] = zz;

    const int ks  = lane >> 4;
    const int r16 = lane & 15;
    const int cidx = ks ^ (r16 & 3) ^ ((r16 >> 2) & 3);   // mf-independent

#define ISSUE(kn, bi) do {                                                  \
    int g_  = (kn) >> 2;                                                    \
    int di_ = (g_ * 11) >> 5;                                               \
    int dj_ = g_ - 3 * di_;                                                 \
    int aoff_ = (di_ * W_ + dj_) * C_ + ((kn) & 3) * 32 + kco;              \
    gload16(a_base + aoff_, &As[bi][0] + a_dst);                            \
    const u16* bsrc_ = wt + (kn) * 8192 + t * 8;                            \
    gload16(bsrc_,        &Bs[bi][0] + b_dst);                              \
    gload16(bsrc_ + 2048, &Bs[bi][0] + b_dst + 2048);                       \
    gload16(bsrc_ + 4096, &Bs[bi][0] + b_dst + 4096);                       \
    gload16(bsrc_ + 6144, &Bs[bi][0] + b_dst + 6144);                       \
} while (0)

#define COMPUTE(bi) do {                                                    \
    bf16x8 a_[4], b_[4];                                                    \
    _Pragma("unroll")                                                       \
    for (int mf = 0; mf < 4; ++mf)                                          \
        a_[mf] = *(const bf16x8*)(&As[bi][(mf * 16 + r16) * 32 + cidx * 8]);\
    _Pragma("unroll")                                                       \
    for (int nf = 0; nf < 4; ++nf)                                          \
        b_[nf] = *(const bf16x8*)(&Bs[bi][(ks * 256 + wid * 64 + nf * 16 + r16) * 8]); \
    _Pragma("unroll")                                                       \
    for (int mf = 0; mf < 4; ++mf)                                          \
        _Pragma("unroll")                                                   \
        for (int nf = 0; nf < 4; ++nf)                                      \
            acc[mf][nf] = __builtin_amdgcn_mfma_f32_16x16x32_bf16(          \
                a_[mf], b_[nf], acc[mf][nf], 0, 0, 0);                      \
} while (0)

#define WAITVM(n) asm volatile("s_waitcnt vmcnt(" #n ")" ::: "memory")
#define BAR() do { __builtin_amdgcn_s_barrier();                            \
                   __builtin_amdgcn_sched_barrier(0); } while (0)

    // prologue: 3 tiles in flight
    ISSUE(0, 0);
    ISSUE(1, 1);
    ISSUE(2, 2);

    // main loop: iters 0..31, issue tiles 3..34
    for (int kt0 = 0; kt0 < 32; kt0 += 4) {
        WAITVM(10); BAR(); COMPUTE(0); ISSUE(kt0 + 3, 3);
        WAITVM(10); BAR(); COMPUTE(1); ISSUE(kt0 + 4, 0);
        WAITVM(10); BAR(); COMPUTE(2); ISSUE(kt0 + 5, 1);
        WAITVM(10); BAR(); COMPUTE(3); ISSUE(kt0 + 6, 2);
    }
    // epilogue: iters 32..35 (issue 35, then drain 10/5/0)
    WAITVM(10); BAR(); COMPUTE(0); ISSUE(35, 3);
    WAITVM(10); BAR(); COMPUTE(1);
    WAITVM(5);  BAR(); COMPUTE(2);
    WAITVM(0);  BAR(); COMPUTE(3);

#undef ISSUE
#undef COMPUTE
#undef WAITVM
#undef BAR

    // epilogue: C/D layout col = lane&15, row = (lane>>4)*4 + reg (m89-verified)
    const int rgrp = lane >> 4;
#pragma unroll
    for (int nf = 0; nf < 4; ++nf) {
        int col  = wid * 64 + nf * 16 + r16;
        float bv = bias[col];
#pragma unroll
        for (int mf = 0; mf < 4; ++mf) {
#pragma unroll
            for (int rr = 0; rr < 4; ++rr) {
                int row = m0 + mf * 16 + rgrp * 4 + rr;
                float v = acc[mf][nf][rr] + bv;
                out[row * NF_ + col] = fmaxf(v, 0.f);
            }
        }
    }
}

extern "C" void kernel_launch(void* const* d_in, const int* in_sizes, int n_in,
                              void* d_out, int out_size, void* d_ws, size_t ws_size,
                              hipStream_t stream) {
    const float* x    = (const float*)d_in[0];
    const float* kv   = (const float*)d_in[1];
    const float* bias = (const float*)d_in[2];
    const int*   idx  = (const int*)d_in[3];
    float* out = (float*)d_out;

    u16* xb  = (u16*)d_ws;
    u16* wtp = (u16*)((char*)d_ws + (size_t)XB_ELEMS * 2);

    hipMemsetAsync(wtp, 0, (size_t)WT_ELEMS * 2, stream);
    cvt_x_kernel<<<XB_ELEMS / (256 * 8), 256, 0, stream>>>(x, xb);
    scatter_kernel<<<(NNZ_ + 255) / 256, 256, 0, stream>>>(kv, idx, wtp);
    spconv_gemm<<<M_ / 64, 256, 0, stream>>>(xb, wtp, bias, out);
}

// Round 5
// 50.701 us; speedup vs baseline: 1.2407x; 1.2407x over previous
//
#include <hip/hip_runtime.h>

typedef unsigned short u16;
typedef __bf16 bf16x8 __attribute__((ext_vector_type(8)));
typedef float f32x4 __attribute__((ext_vector_type(4)));

#define B_   16
#define H_   56
#define W_   56
#define C_   128
#define OH_  54
#define OW_  54
#define NF_  256
#define KF_  1152           // C_*9
#define M_   46656          // B_*OH_*OW_
#define NNZ_ 58982

#define XB_ELEMS (B_*H_*W_*C_)       // 6422528
#define WT_ELEMS (36*4*256*8)        // 294912 (pre-tiled [kt][ks][col][8])

__device__ __forceinline__ u16 f2bf(float f) {
    unsigned u = __float_as_uint(f);
    u += 0x7FFFu + ((u >> 16) & 1u);
    return (u16)(u >> 16);
}

__device__ __forceinline__ void gload16(const void* g, void* l) {
    __builtin_amdgcn_global_load_lds(
        (const __attribute__((address_space(1))) unsigned int*)g,
        (__attribute__((address_space(3))) unsigned int*)l,
        16, 0, 0);
}

// ---- kernel 1: x f32 -> bf16 (vectorized 8/thread) ----
__global__ __launch_bounds__(256) void cvt_x_kernel(const float* __restrict__ x,
                                                    u16* __restrict__ xb) {
    int i = (blockIdx.x * 256 + threadIdx.x) * 8;
    float4 v0 = *(const float4*)(x + i);
    float4 v1 = *(const float4*)(x + i + 4);
    union { u16 u[8]; uint4 v; } r;
    r.u[0] = f2bf(v0.x); r.u[1] = f2bf(v0.y); r.u[2] = f2bf(v0.z); r.u[3] = f2bf(v0.w);
    r.u[4] = f2bf(v1.x); r.u[5] = f2bf(v1.y); r.u[6] = f2bf(v1.z); r.u[7] = f2bf(v1.w);
    *(uint4*)(xb + i) = r.v;
}

// ---- kernel 2: scatter sparse values into PRE-TILED W: [kt][ks][col][8] ----
__global__ __launch_bounds__(256) void scatter_kernel(const float* __restrict__ kv,
                                                      const int* __restrict__ idx,
                                                      u16* __restrict__ wt) {
    int t = blockIdx.x * 256 + threadIdx.x;
    if (t >= NNZ_) return;
    int k   = idx[2*t];      // row in [0,1152)
    int col = idx[2*t + 1];  // col in [0,256)
    int kt = k >> 5, ks = (k >> 3) & 3, e = k & 7;
    wt[(kt * 4 + ks) * 2048 + col * 8 + e] = f2bf(kv[t]);
}

// ---- kernel 3: implicit-GEMM conv, 2-deep dbuf + COUNTED vmcnt (T4) ----
// BM=64 (729 blocks exact), BN=256, BK=32, 4 waves of 64x64. 40KB LDS
// (~2.85 blocks/CU resident). Per iter: vmcnt(5) [tile k done, k+1 in
// flight] -> s_barrier -> compute buf[k&1] -> s_barrier -> issue tile k+2
// into buf[k&1]. vmcnt NEVER drains to 0 in the main loop. Fully unrolled.
__global__ __launch_bounds__(256) void spconv_gemm(const u16* __restrict__ xb,
                                                   const u16* __restrict__ wt,
                                                   const float* __restrict__ bias,
                                                   float* __restrict__ out) {
    __shared__ __align__(16) u16 As[2][64 * 32];      // 2 x 4 KB
    __shared__ __align__(16) u16 Bs[2][4 * 256 * 8];  // 2 x 16 KB

    const int t    = threadIdx.x;
    const int lane = t & 63;
    const int wid  = t >> 6;

    // bijective XCD swizzle (nwg=729 -> m204 formula)
    const int nwg = gridDim.x;
    const int q = nwg >> 3, r = nwg & 7;
    const int xcd = blockIdx.x & 7, inner = blockIdx.x >> 3;
    const int wg = (xcd < r ? xcd * (q + 1) : r * (q + 1) + (xcd - r) * q) + inner;
    const int m0 = wg * 64;

    // A staging: thread t stages cell (arow, kc); 4 lanes/row -> 64B sectors.
    // kc-XOR swizzle applied on the global SOURCE (dest stays lane-linear).
    const int arow = (wid << 4) | (lane >> 2);          // 0..63
    const int kc   = lane & 3;
    const int kcs  = kc ^ (arow & 3) ^ ((arow >> 2) & 3);
    const int kco  = kcs * 8;
    int mg  = m0 + arow;
    int bb  = mg / (OH_ * OW_);
    int rem = mg % (OH_ * OW_);
    int ii  = rem / OW_;
    int jj  = rem % OW_;
    const u16* a_base = xb + ((bb * H_ + ii) * W_ + jj) * C_;
    const int a_dst = t * 8;
    const int b_dst = t * 8;

    f32x4 acc[4][4];
    const f32x4 zz = {0.f, 0.f, 0.f, 0.f};
#pragma unroll
    for (int i = 0; i < 4; ++i)
#pragma unroll
        for (int j = 0; j < 4; ++j) acc[i][j] = zz;

    const int ks  = lane >> 4;
    const int r16 = lane & 15;
    const int cidx = ks ^ (r16 & 3) ^ ((r16 >> 2) & 3);   // mf-independent

#define ISSUE(kn, bi) do {                                                  \
    int g_  = (kn) >> 2;                                                    \
    int di_ = (g_ * 11) >> 5;                                               \
    int dj_ = g_ - 3 * di_;                                                 \
    int aoff_ = (di_ * W_ + dj_) * C_ + ((kn) & 3) * 32 + kco;              \
    gload16(a_base + aoff_, &As[bi][0] + a_dst);                            \
    const u16* bsrc_ = wt + (kn) * 8192 + t * 8;                            \
    gload16(bsrc_,        &Bs[bi][0] + b_dst);                              \
    gload16(bsrc_ + 2048, &Bs[bi][0] + b_dst + 2048);                       \
    gload16(bsrc_ + 4096, &Bs[bi][0] + b_dst + 4096);                       \
    gload16(bsrc_ + 6144, &Bs[bi][0] + b_dst + 6144);                       \
} while (0)

#define COMPUTE(bi) do {                                                    \
    bf16x8 a_[4], b_[4];                                                    \
    _Pragma("unroll")                                                       \
    for (int mf = 0; mf < 4; ++mf)                                          \
        a_[mf] = *(const bf16x8*)(&As[bi][(mf * 16 + r16) * 32 + cidx * 8]);\
    _Pragma("unroll")                                                       \
    for (int nf = 0; nf < 4; ++nf)                                          \
        b_[nf] = *(const bf16x8*)(&Bs[bi][(ks * 256 + wid * 64 + nf * 16 + r16) * 8]); \
    _Pragma("unroll")                                                       \
    for (int mf = 0; mf < 4; ++mf)                                          \
        _Pragma("unroll")                                                   \
        for (int nf = 0; nf < 4; ++nf)                                      \
            acc[mf][nf] = __builtin_amdgcn_mfma_f32_16x16x32_bf16(          \
                a_[mf], b_[nf], acc[mf][nf], 0, 0, 0);                      \
} while (0)

// counted waits; "memory" clobber doubles as a compiler fence so LDS reads
// can't hoist above the wait/barrier pair (rule #18 analog, zero runtime cost)
#define WAITVM(n) asm volatile("s_waitcnt vmcnt(" #n ")" ::: "memory")
#define BAR() do { __builtin_amdgcn_s_barrier();                            \
                   asm volatile("" ::: "memory"); } while (0)

    // prologue: 2 tiles in flight
    ISSUE(0, 0);
    ISSUE(1, 1);

    // main loop, fully unrolled: iters 0..33 issue tiles 2..35
#pragma unroll
    for (int k = 0; k < 34; ++k) {
        WAITVM(5);            // tile k landed; tile k+1 stays in flight
        BAR();                // all waves' tile-k staging visible
        COMPUTE(k & 1);
        BAR();                // all waves done reading buf[k&1]
        ISSUE(k + 2, k & 1);  // overwrite it with tile k+2
    }
    // tail: iters 34, 35
    WAITVM(5); BAR(); COMPUTE(0); BAR();
    WAITVM(0); BAR(); COMPUTE(1);

#undef ISSUE
#undef COMPUTE
#undef WAITVM
#undef BAR

    // epilogue: C/D layout col = lane&15, row = (lane>>4)*4 + reg (m89-verified)
    const int rgrp = lane >> 4;
#pragma unroll
    for (int nf = 0; nf < 4; ++nf) {
        int col  = wid * 64 + nf * 16 + r16;
        float bv = bias[col];
#pragma unroll
        for (int mf = 0; mf < 4; ++mf) {
#pragma unroll
            for (int rr = 0; rr < 4; ++rr) {
                int row = m0 + mf * 16 + rgrp * 4 + rr;
                float v = acc[mf][nf][rr] + bv;
                out[row * NF_ + col] = fmaxf(v, 0.f);
            }
        }
    }
}

extern "C" void kernel_launch(void* const* d_in, const int* in_sizes, int n_in,
                              void* d_out, int out_size, void* d_ws, size_t ws_size,
                              hipStream_t stream) {
    const float* x    = (const float*)d_in[0];
    const float* kv   = (const float*)d_in[1];
    const float* bias = (const float*)d_in[2];
    const int*   idx  = (const int*)d_in[3];
    float* out = (float*)d_out;

    u16* xb  = (u16*)d_ws;
    u16* wtp = (u16*)((char*)d_ws + (size_t)XB_ELEMS * 2);

    hipMemsetAsync(wtp, 0, (size_t)WT_ELEMS * 2, stream);
    cvt_x_kernel<<<XB_ELEMS / (256 * 8), 256, 0, stream>>>(x, xb);
    scatter_kernel<<<(NNZ_ + 255) / 256, 256, 0, stream>>>(kv, idx, wtp);
    spconv_gemm<<<M_ / 64, 256, 0, stream>>>(xb, wtp, bias, out);
}